// Round 20
// baseline (122.777 us; speedup 1.0000x reference)
//
#include <hip/hip_runtime.h>
#include <math.h>

#define D_DIM 4096
#define NWG 1024  // 4 WGs/CU x 256 CUs, persistent grid-stride (16 rows/WG)

typedef float v2f __attribute__((ext_vector_type(2)));

// ---- packed-f32 butterfly primitives (VOP3P) ----
__device__ __forceinline__ v2f bfly0(v2f a) {
    v2f d;
    asm("v_pk_add_f32 %0, %1, %2 op_sel:[0,1] op_sel_hi:[0,1] neg_hi:[0,1]"
        : "=v"(d) : "v"(a), "v"(a));
    return d;
}
__device__ __forceinline__ v2f pkadd(v2f a, v2f b) {
    v2f d; asm("v_pk_add_f32 %0, %1, %2" : "=v"(d) : "v"(a), "v"(b)); return d;
}
__device__ __forceinline__ v2f pksub(v2f a, v2f b) {
    v2f d; asm("v_pk_add_f32 %0, %1, %2 neg_lo:[0,1] neg_hi:[0,1]" : "=v"(d) : "v"(a), "v"(b)); return d;
}
__device__ __forceinline__ v2f pkmul(v2f a, v2f b) {
    v2f d; asm("v_pk_mul_f32 %0, %1, %2" : "=v"(d) : "v"(a), "v"(b)); return d;
}

// In-register FWHT over 4 bits: 16 values as 8 packed v2f.
__device__ __forceinline__ void radix16(v2f w[8]) {
#pragma unroll
    for (int p = 0; p < 8; ++p) w[p] = bfly0(w[p]);
#pragma unroll
    for (int s = 0; s < 3; ++s) {
        const int d = 1 << s;
#pragma unroll
        for (int p = 0; p < 8; ++p) {
            if (!(p & d)) {
                const v2f a = w[p];
                const v2f b = w[p + d];
                w[p]     = pkadd(a, b);
                w[p + d] = pksub(a, b);
            }
        }
    }
}

// async global->LDS, 16 B per lane; LDS dest = wave-uniform base + lane*16.
__device__ __forceinline__ void gload_lds16(const float* g, float* lp) {
    __builtin_amdgcn_global_load_lds(
        (const __attribute__((address_space(1))) void*)g,
        (__attribute__((address_space(3))) void*)lp, 16, 0, 0);
}

// Phase barrier: drain DS ops only (NOT vmcnt -> glds prefetch stays in
// flight across barriers; __syncthreads would emit vmcnt(0) and kill it).
__device__ __forceinline__ void phase_barrier() {
    asm volatile("s_waitcnt lgkmcnt(0)" ::: "memory");
    __builtin_amdgcn_s_barrier();
    __builtin_amdgcn_sched_barrier(0);
}

// Rank-complete transpose-buffer swizzle (verified R11/R15; same 3 patterns):
//   b4 ^= e8 ^ e5 ;  b3 ^= e7 ;  b2 ^= e9 ^ e6
// - contig b128 (A/E + stage reads): at the b128 bank floor
// - stride-16 (B/D): 2-way banks (free)
// - stride-256 (C):  2-way banks (free)
// Bijective involution; word bits 1:0 untouched -> any aligned 4-word block
// maps to an aligned 4-word block (b128 + pre-swizzled glds source both OK).
__device__ __forceinline__ int swzW(int e) {
    const int x4 = ((e >> 8) ^ (e >> 5)) & 1;
    const int x3 = (e >> 7) & 1;
    const int x2 = ((e >> 9) ^ (e >> 6)) & 1;
    return e ^ (x4 << 4) ^ (x3 << 3) ^ (x2 << 2);
}

// u in NATURAL order, 1/64 FWHT normalization folded in.
__global__ void compute_u_kernel(const float* __restrict__ g_mu,
                                 const float* __restrict__ g_rho,
                                 const float* __restrict__ eps,
                                 float* __restrict__ u) {
    const int i = blockIdx.x * blockDim.x + threadIdx.x;
    if (i < D_DIM) {
        const float r = g_rho[i];
        const float sp = (r > 20.0f) ? r : log1pf(expf(r));
        u[i] = (g_mu[i] + sp * eps[i]) * 0.015625f;
    }
}

// Persistent cooperative kernel: R11 skeleton (compiler-visible LDS ops,
// lgkm-only barriers, counted vmcnt) with REORDERED FWHT stages so the edge
// phases are contiguous-per-thread (bit-stages commute):
//   A: bits 0-3  (stage b128 reads -> trb b128 writes), *s2
//   B: bits 4-7  (stride-16, in place)
//   C: bits 8-11, *u, bits 8-11 (stride-256, in place)
//   D: bits 4-7  (stride-16, in place)
//   E: bits 0-3  (trb b128 reads), *s1, float4 global stores (4 per thread)
// Stage content is PRE-SWIZZLED via the glds SOURCE address (linear LDS dest,
// guide-verified pattern; correctness proven in R16's passing run).
// Bottom vmem queue (oldest->newest): 4 glds, 4 stores; vmcnt(4) retires
// exactly the glds, keeps stores in flight.
__global__ __launch_bounds__(256, 4) void whvi_kernel(const float* __restrict__ x,
                                                      const float* __restrict__ s1,
                                                      const float* __restrict__ s2,
                                                      const float* __restrict__ u,
                                                      float* __restrict__ out,
                                                      int nrows) {
    __shared__ float stg[D_DIM];  // x stage: linear glds dest, pre-swizzled content
    __shared__ float trb[D_DIM];  // transpose buffer: swzW layout
    const int tid = threadIdx.x;
    const int wv = tid >> 6;
    const int l6 = tid & 63;
    const int cb = tid << 4;  // contiguous per-thread base (phases A/E)

    // ---- persistent scales: s1/s2 contiguous (float4), u stride-256 ----
    float4 S1f[4], S2f[4];
#pragma unroll
    for (int c = 0; c < 4; ++c) {
        S1f[c] = *reinterpret_cast<const float4*>(s1 + cb + (c << 2));
        S2f[c] = *reinterpret_cast<const float4*>(s2 + cb + (c << 2));
    }
    float Ur[16];
#pragma unroll
    for (int m = 0; m < 16; ++m) Ur[m] = u[tid + (m << 8)];

    // ---- prologue: glds row0 into stage (pre-swizzled source), drain ----
    int row = blockIdx.x;
    if (row < nrows) {
        const float* xr = x + (size_t)row * D_DIM;
#pragma unroll
        for (int k = 0; k < 4; ++k) {
            const int B = (k << 10) | (wv << 8);
            gload_lds16(xr + swzW(B + (l6 << 2)), &stg[B]);
        }
    }
    asm volatile("s_waitcnt vmcnt(0)" ::: "memory");
    __builtin_amdgcn_s_barrier();
    __builtin_amdgcn_sched_barrier(0);

    for (; row < nrows; row += NWG) {
        const int next = row + NWG;
        v2f w[8];

        // ---- Phase A: stage b128 reads (swz addr -> linear content), *s2,
        //      FWHT bits 0-3, trb b128 writes ----
        {
#pragma unroll
            for (int c = 0; c < 4; ++c) {
                const float4 f = *reinterpret_cast<const float4*>(&stg[swzW(cb | (c << 2))]);
                w[2 * c]     = pkmul((v2f){f.x, f.y}, (v2f){S2f[c].x, S2f[c].y});
                w[2 * c + 1] = pkmul((v2f){f.z, f.w}, (v2f){S2f[c].z, S2f[c].w});
            }
            radix16(w);
#pragma unroll
            for (int c = 0; c < 4; ++c) {
                const float4 f = make_float4(w[2 * c].x, w[2 * c].y,
                                             w[2 * c + 1].x, w[2 * c + 1].y);
                *reinterpret_cast<float4*>(&trb[swzW(cb | (c << 2))]) = f;
            }
        }
        phase_barrier();  // also: all waves done READING stg

        // ---- prefetch next row into stage (stays in flight all row) ----
        if (next < nrows) {
            const float* xn = x + (size_t)next * D_DIM;
#pragma unroll
            for (int k = 0; k < 4; ++k) {
                const int B = (k << 10) | (wv << 8);
                gload_lds16(xn + swzW(B + (l6 << 2)), &stg[B]);
            }
        }
        __builtin_amdgcn_sched_barrier(0);

        // ---- Phase B: FWHT bits 4-7 (stride-16, in place) ----
        {
            const int base = ((tid >> 4) << 8) | (tid & 15);
#pragma unroll
            for (int m = 0; m < 16; ++m) {
                const float val = trb[swzW(base | (m << 4))];
                if (m & 1) w[m >> 1].y = val; else w[m >> 1].x = val;
            }
            radix16(w);
#pragma unroll
            for (int m = 0; m < 16; ++m)
                trb[swzW(base | (m << 4))] = (m & 1) ? w[m >> 1].y : w[m >> 1].x;
        }
        phase_barrier();

        // ---- Phase C: FWHT bits 8-11, *u, FWHT bits 8-11 (stride-256) ----
        {
#pragma unroll
            for (int m = 0; m < 16; ++m) {
                const float val = trb[swzW(tid + (m << 8))];
                if (m & 1) w[m >> 1].y = val; else w[m >> 1].x = val;
            }
            radix16(w);
#pragma unroll
            for (int p = 0; p < 8; ++p)
                w[p] = pkmul(w[p], (v2f){Ur[2 * p], Ur[2 * p + 1]});
            radix16(w);
#pragma unroll
            for (int m = 0; m < 16; ++m)
                trb[swzW(tid + (m << 8))] = (m & 1) ? w[m >> 1].y : w[m >> 1].x;
        }
        phase_barrier();

        // ---- Phase D: FWHT bits 4-7 (stride-16, in place) ----
        {
            const int base = ((tid >> 4) << 8) | (tid & 15);
#pragma unroll
            for (int m = 0; m < 16; ++m) {
                const float val = trb[swzW(base | (m << 4))];
                if (m & 1) w[m >> 1].y = val; else w[m >> 1].x = val;
            }
            radix16(w);
#pragma unroll
            for (int m = 0; m < 16; ++m)
                trb[swzW(base | (m << 4))] = (m & 1) ? w[m >> 1].y : w[m >> 1].x;
        }
        phase_barrier();

        // ---- Phase E: trb b128 reads, FWHT bits 0-3, *s1, float4 stores ----
        {
#pragma unroll
            for (int c = 0; c < 4; ++c) {
                const float4 f = *reinterpret_cast<const float4*>(&trb[swzW(cb | (c << 2))]);
                w[2 * c]     = (v2f){f.x, f.y};
                w[2 * c + 1] = (v2f){f.z, f.w};
            }
            radix16(w);
            float* orow = out + (size_t)row * D_DIM;
#pragma unroll
            for (int c = 0; c < 4; ++c) {
                const v2f o0 = pkmul(w[2 * c],     (v2f){S1f[c].x, S1f[c].y});
                const v2f o1 = pkmul(w[2 * c + 1], (v2f){S1f[c].z, S1f[c].w});
                *reinterpret_cast<float4*>(orow + cb + (c << 2)) =
                    make_float4(o0.x, o0.y, o1.x, o1.y);
            }
        }

        // ---- bottom: retire exactly the 4 glds (keep 4 stores in flight),
        //      then barrier (trb reuse by next A + stage readiness) ----
        asm volatile("s_waitcnt vmcnt(4)" ::: "memory");
        asm volatile("s_waitcnt lgkmcnt(0)" ::: "memory");
        __builtin_amdgcn_s_barrier();
        __builtin_amdgcn_sched_barrier(0);
    }
}

extern "C" void kernel_launch(void* const* d_in, const int* in_sizes, int n_in,
                              void* d_out, int out_size, void* d_ws, size_t ws_size,
                              hipStream_t stream) {
    const float* x     = (const float*)d_in[0];
    const float* s1    = (const float*)d_in[1];
    const float* s2    = (const float*)d_in[2];
    const float* g_mu  = (const float*)d_in[3];
    const float* g_rho = (const float*)d_in[4];
    const float* eps   = (const float*)d_in[5];
    // d_in[6] = H : realized implicitly by the FWHT butterflies.

    float* u   = (float*)d_ws;
    float* out = (float*)d_out;

    const int N = in_sizes[0] / D_DIM;

    compute_u_kernel<<<(D_DIM + 255) / 256, 256, 0, stream>>>(g_mu, g_rho, eps, u);
    whvi_kernel<<<NWG, 256, 0, stream>>>(x, s1, s2, u, out, N);
}

// Round 21
// 113.963 us; speedup vs baseline: 1.0773x; 1.0773x over previous
//
#include <hip/hip_runtime.h>
#include <math.h>

#define D_DIM 4096
#define NWG 1024  // 4 WGs/CU x 256 CUs, persistent grid-stride (16 rows/WG)

typedef float v2f __attribute__((ext_vector_type(2)));

// ---- packed-f32 butterfly primitives (VOP3P) ----
__device__ __forceinline__ v2f bfly0(v2f a) {
    v2f d;
    asm("v_pk_add_f32 %0, %1, %2 op_sel:[0,1] op_sel_hi:[0,1] neg_hi:[0,1]"
        : "=v"(d) : "v"(a), "v"(a));
    return d;
}
__device__ __forceinline__ v2f pkadd(v2f a, v2f b) {
    v2f d; asm("v_pk_add_f32 %0, %1, %2" : "=v"(d) : "v"(a), "v"(b)); return d;
}
__device__ __forceinline__ v2f pksub(v2f a, v2f b) {
    v2f d; asm("v_pk_add_f32 %0, %1, %2 neg_lo:[0,1] neg_hi:[0,1]" : "=v"(d) : "v"(a), "v"(b)); return d;
}
__device__ __forceinline__ v2f pkmul(v2f a, v2f b) {
    v2f d; asm("v_pk_mul_f32 %0, %1, %2" : "=v"(d) : "v"(a), "v"(b)); return d;
}

// In-register FWHT over 4 bits: 16 values as 8 packed v2f.
__device__ __forceinline__ void radix16(v2f w[8]) {
#pragma unroll
    for (int p = 0; p < 8; ++p) w[p] = bfly0(w[p]);
#pragma unroll
    for (int s = 0; s < 3; ++s) {
        const int d = 1 << s;
#pragma unroll
        for (int p = 0; p < 8; ++p) {
            if (!(p & d)) {
                const v2f a = w[p];
                const v2f b = w[p + d];
                w[p]     = pkadd(a, b);
                w[p + d] = pksub(a, b);
            }
        }
    }
}

// async global->LDS, 16 B per lane; LDS dest = wave-uniform base + lane*16.
__device__ __forceinline__ void gload_lds16(const float* g, float* lp) {
    __builtin_amdgcn_global_load_lds(
        (const __attribute__((address_space(1))) void*)g,
        (__attribute__((address_space(3))) void*)lp, 16, 0, 0);
}

// Phase barrier: drain DS ops only (NOT vmcnt -> glds prefetch stays in
// flight across barriers; __syncthreads would emit vmcnt(0) and kill it).
__device__ __forceinline__ void phase_barrier() {
    asm volatile("s_waitcnt lgkmcnt(0)" ::: "memory");
    __builtin_amdgcn_s_barrier();
    __builtin_amdgcn_sched_barrier(0);
}

// Rank-complete transpose-buffer swizzle (re-derived per access pattern):
//   b4 ^= e8 ^ e5 ;  b3 ^= e7 ;  b2 ^= e9 ^ e6
// - Phase A/E (e = m<<8 | tid):      2-way banks (free)
// - Phase B/D (e = t74<<8|m<<4|t30): 2-way banks (free)
// - Phase C   (e = tid<<4|c<<2|j):   exactly the b128 bank floor
// Triangular XOR (high bits into low) -> bijective involution; bits 1:0
// untouched -> b128 contiguity + 16B alignment preserved.
__device__ __forceinline__ int swzW(int e) {
    const int x4 = ((e >> 8) ^ (e >> 5)) & 1;
    const int x3 = (e >> 7) & 1;
    const int x2 = ((e >> 9) ^ (e >> 6)) & 1;
    return e ^ (x4 << 4) ^ (x3 << 3) ^ (x2 << 2);
}

// u in NATURAL order, 1/64 FWHT normalization folded in.
__global__ void compute_u_kernel(const float* __restrict__ g_mu,
                                 const float* __restrict__ g_rho,
                                 const float* __restrict__ eps,
                                 float* __restrict__ u) {
    const int i = blockIdx.x * blockDim.x + threadIdx.x;
    if (i < D_DIM) {
        const float r = g_rho[i];
        const float sp = (r > 20.0f) ? r : log1pf(expf(r));
        u[i] = (g_mu[i] + sp * eps[i]) * 0.015625f;
    }
}

// Persistent cooperative kernel (verified best: R11/R19, 112.2-112.3 us).
// 256 threads/row; stage buffer (16 KB, linear glds dest) + transpose buffer
// (16 KB, swzW). Phases per row: A: *s2, bits 8-11 (stage->trb); B: bits 4-7;
// C: bits 0-3, *u, bits 0-3 (b128); D: bits 4-7; E: bits 8-11, *s1, store.
// Per-wave vmem queue at bottom (oldest->newest): 4 glds, 16 stores;
// s_waitcnt vmcnt(16) retires exactly the glds, keeps stores in flight.
__global__ __launch_bounds__(256, 4) void whvi_kernel(const float* __restrict__ x,
                                                      const float* __restrict__ s1,
                                                      const float* __restrict__ s2,
                                                      const float* __restrict__ u,
                                                      float* __restrict__ out,
                                                      int nrows) {
    __shared__ float stg[D_DIM];  // x stage: linear (glds destination)
    __shared__ float trb[D_DIM];  // transpose buffer: swzW layout
    const int tid = threadIdx.x;
    const int wv = tid >> 6;
    const int l6 = tid & 63;

    // ---- persistent scale registers (fits: ~110 live < 128 VGPR cap) ----
    float S2r[16], S1r[16];
#pragma unroll
    for (int m = 0; m < 16; ++m) {
        S2r[m] = s2[tid + (m << 8)];
        S1r[m] = s1[tid + (m << 8)];
    }
    float4 U4[4];
#pragma unroll
    for (int c = 0; c < 4; ++c)
        U4[c] = *reinterpret_cast<const float4*>(u + (tid << 4) + (c << 2));

    // ---- prologue: glds row0 into stage, drain, barrier ----
    int row = blockIdx.x;
    if (row < nrows) {
        const float* xr = x + (size_t)row * D_DIM;
#pragma unroll
        for (int k = 0; k < 4; ++k)
            gload_lds16(xr + (k << 10) + (wv << 8) + (l6 << 2),
                        &stg[(k << 10) + (wv << 8)]);
    }
    asm volatile("s_waitcnt vmcnt(0)" ::: "memory");
    __builtin_amdgcn_s_barrier();
    __builtin_amdgcn_sched_barrier(0);

    for (; row < nrows; row += NWG) {
        const int next = row + NWG;
        v2f w[8];

        // ---- Phase A: read stage (linear), *s2, FWHT bits 8-11, write trb ----
#pragma unroll
        for (int m = 0; m < 16; ++m) {
            const float val = stg[tid + (m << 8)] * S2r[m];
            if (m & 1) w[m >> 1].y = val; else w[m >> 1].x = val;
        }
        radix16(w);
#pragma unroll
        for (int m = 0; m < 16; ++m)
            trb[swzW(tid + (m << 8))] = (m & 1) ? w[m >> 1].y : w[m >> 1].x;
        phase_barrier();  // also: all waves done READING stg

        // ---- prefetch next row into stage (stays in flight all row) ----
        if (next < nrows) {
            const float* xn = x + (size_t)next * D_DIM;
#pragma unroll
            for (int k = 0; k < 4; ++k)
                gload_lds16(xn + (k << 10) + (wv << 8) + (l6 << 2),
                            &stg[(k << 10) + (wv << 8)]);
        }
        __builtin_amdgcn_sched_barrier(0);

        // ---- Phase B: FWHT bits 4-7, in place ----
        {
            const int base = ((tid >> 4) << 8) | (tid & 15);
#pragma unroll
            for (int m = 0; m < 16; ++m) {
                const float val = trb[swzW(base | (m << 4))];
                if (m & 1) w[m >> 1].y = val; else w[m >> 1].x = val;
            }
            radix16(w);
#pragma unroll
            for (int m = 0; m < 16; ++m)
                trb[swzW(base | (m << 4))] = (m & 1) ? w[m >> 1].y : w[m >> 1].x;
        }
        phase_barrier();

        // ---- Phase C: FWHT bits 0-3, *u, FWHT bits 0-3 (b128, in place) ----
        {
            const int cb = tid << 4;
#pragma unroll
            for (int c = 0; c < 4; ++c) {
                const float4 f = *reinterpret_cast<const float4*>(&trb[swzW(cb | (c << 2))]);
                w[2 * c]     = (v2f){f.x, f.y};
                w[2 * c + 1] = (v2f){f.z, f.w};
            }
            radix16(w);
#pragma unroll
            for (int c = 0; c < 4; ++c) {
                w[2 * c]     = pkmul(w[2 * c],     (v2f){U4[c].x, U4[c].y});
                w[2 * c + 1] = pkmul(w[2 * c + 1], (v2f){U4[c].z, U4[c].w});
            }
            radix16(w);
#pragma unroll
            for (int c = 0; c < 4; ++c) {
                const float4 f = make_float4(w[2 * c].x, w[2 * c].y,
                                             w[2 * c + 1].x, w[2 * c + 1].y);
                *reinterpret_cast<float4*>(&trb[swzW(cb | (c << 2))]) = f;
            }
        }
        phase_barrier();

        // ---- Phase D: FWHT bits 4-7, in place ----
        {
            const int base = ((tid >> 4) << 8) | (tid & 15);
#pragma unroll
            for (int m = 0; m < 16; ++m) {
                const float val = trb[swzW(base | (m << 4))];
                if (m & 1) w[m >> 1].y = val; else w[m >> 1].x = val;
            }
            radix16(w);
#pragma unroll
            for (int m = 0; m < 16; ++m)
                trb[swzW(base | (m << 4))] = (m & 1) ? w[m >> 1].y : w[m >> 1].x;
        }
        phase_barrier();

        // ---- Phase E: FWHT bits 8-11, *s1, coalesced b32 stores ----
#pragma unroll
        for (int m = 0; m < 16; ++m) {
            const float val = trb[swzW(tid + (m << 8))];
            if (m & 1) w[m >> 1].y = val; else w[m >> 1].x = val;
        }
        radix16(w);
        float* orow = out + (size_t)row * D_DIM;
#pragma unroll
        for (int m = 0; m < 16; ++m) {
            const float val = (m & 1) ? w[m >> 1].y : w[m >> 1].x;
            orow[tid + (m << 8)] = val * S1r[m];
        }

        // ---- bottom: retire exactly the glds (keep stores in flight),
        //      then barrier (trb reuse by next A + stage readiness) ----
        asm volatile("s_waitcnt vmcnt(16)" ::: "memory");
        asm volatile("s_waitcnt lgkmcnt(0)" ::: "memory");
        __builtin_amdgcn_s_barrier();
        __builtin_amdgcn_sched_barrier(0);
    }
}

extern "C" void kernel_launch(void* const* d_in, const int* in_sizes, int n_in,
                              void* d_out, int out_size, void* d_ws, size_t ws_size,
                              hipStream_t stream) {
    const float* x     = (const float*)d_in[0];
    const float* s1    = (const float*)d_in[1];
    const float* s2    = (const float*)d_in[2];
    const float* g_mu  = (const float*)d_in[3];
    const float* g_rho = (const float*)d_in[4];
    const float* eps   = (const float*)d_in[5];
    // d_in[6] = H : realized implicitly by the FWHT butterflies.

    float* u   = (float*)d_ws;
    float* out = (float*)d_out;

    const int N = in_sizes[0] / D_DIM;

    compute_u_kernel<<<(D_DIM + 255) / 256, 256, 0, stream>>>(g_mu, g_rho, eps, u);
    whvi_kernel<<<NWG, 256, 0, stream>>>(x, s1, s2, u, out, N);
}